// Round 4
// baseline (93.398 us; speedup 1.0000x reference)
//
#include <hip/hip_runtime.h>
#include <hip/hip_bf16.h>
#include <stdint.h>

// out[b,o,p] = sum_{r,c} mat0[b,c,p] * mat1[o,c,r]*Alpha[r] * mask[r,p]
// Single GEMM: M=256 (o), N=32768 (n=b*4096+p), K=2048 (k=c*8+r).
// A[o,k] = mat1[o,c,r]*Alpha[r]  (prepped bf16 in d_ws, layout [c][o][r])
// B[k,n] = mat0[b,c,p]*mask[r,p] synthesized IN REGISTERS per lane.
// Round 4: 512-thread blocks, in-block K-split (wk pairs) -> 4 waves/SIMD,
// 32x32x16 MFMA (fewer matrix-pipe cycles, half the MFMA instrs),
// zero barriers in main loop; one-barrier LDS reduction at epilogue.

typedef __attribute__((ext_vector_type(8)))  short short8;
typedef __attribute__((ext_vector_type(4)))  float f32x4;
typedef __attribute__((ext_vector_type(16))) float f32x16;

#define C_IN  256
#define HW_   4096
#define O_DIM 256
#define BM    128
#define BN    128
#define NRND  32    // K rounds; per round each wk-wave consumes 4 c-planes

__device__ __forceinline__ short f2bf(float x) {
  union { __hip_bfloat16 h; short s; } u;
  u.h = __float2bfloat16(x);   // RNE; compiler pk-fuses into v_cvt_pk_bf16_f32
  return u.s;
}

__global__ __launch_bounds__(256) void prep_w_kernel(
    const float* __restrict__ mat1, const float* __restrict__ Alpha,
    const int* __restrict__ use_alpha, short* __restrict__ Aprep) {
  int t = blockIdx.x * 256 + threadIdx.x;   // o = t&255, c = t>>8
  int o = t & 255;
  int c = t >> 8;
  int ua = use_alpha[0];
  const float* src = mat1 + ((size_t)o * C_IN + c) * 8;
  short8 v;
#pragma unroll
  for (int r = 0; r < 8; ++r) {
    float s = ua ? Alpha[r] : 1.0f;
    v[r] = f2bf(src[r] * s);
  }
  // layout: slot (c*256 + o) holds 8 bf16 (r fastest)
  *(short8*)(Aprep + ((size_t)c * 256 + o) * 8) = v;
}

__global__ __launch_bounds__(512, 4) void gemm_deform_kernel(
    const float* __restrict__ mat0, const short* __restrict__ Aprep,
    const float* __restrict__ mask, float* __restrict__ out) {
  __shared__ float red[8 * 2048];   // 8 regions x 8 KiB = 64 KiB (epilogue only)

  int bid = blockIdx.x;
  int wg = (bid & 7) * 64 + (bid >> 3);   // XCD swizzle (512 % 8 == 0, bijective)
  int tile_m = wg & 1;
  int tile_n = wg >> 1;
  int o0 = tile_m * BM;
  int n0 = tile_n * BN;
  int b  = n0 >> 12;
  int p0 = n0 & 4095;

  int t    = threadIdx.x;
  int lane = t & 63;
  int w    = t >> 6;        // 0..7
  int wk   = w & 1;         // K-half (in-block K-split)
  int wc   = (w >> 1) & 1;  // N-half
  int wr   = w >> 2;        // M-half
  int l31  = lane & 31;     // 32x32 fragment row/col
  int cr   = lane >> 5;     // k-group within fragment (c-plane offset)

  // lane-resident mask values for this lane's 2 fragment columns
  int colb = p0 + wc * 64 + l31;
  float mk[2][8];
#pragma unroll
  for (int ni = 0; ni < 2; ++ni)
#pragma unroll
    for (int r = 0; r < 8; ++r)
      mk[ni][r] = mask[r * HW_ + colb + ni * 32];

  // A fragment source: slot index = c*256 + o  (16B slots)
  const short8* __restrict__ Ap = (const short8*)Aprep;
  int abase0 = (wk * 4 + cr) * 256 + o0 + wr * 64 + l31;  // + rd*2048 + kq*512 + mi*32

  // mat0 source for this lane: c-plane (wk*4+cr), column colb
  const float* __restrict__ m0 =
      mat0 + ((size_t)b * C_IN + wk * 4 + cr) * HW_ + colb;

  f32x16 acc[2][2];
#pragma unroll
  for (int mi = 0; mi < 2; ++mi)
#pragma unroll
    for (int ni = 0; ni < 2; ++ni)
#pragma unroll
      for (int j = 0; j < 16; ++j) acc[mi][ni][j] = 0.f;

  short8 afA[2][2], afB[2][2];   // [kq][mi]
  float  m0A[2][2], m0B[2][2];   // [kq][ni]

  auto LOAD = [&](short8 (&af)[2][2], float (&m0v)[2][2], int rd) {
    int ab = rd * 8 * 256 + abase0;
#pragma unroll
    for (int kq = 0; kq < 2; ++kq)
#pragma unroll
      for (int mi = 0; mi < 2; ++mi)
        af[kq][mi] = Ap[ab + kq * 2 * 256 + mi * 32];
    const float* mp = m0 + (size_t)(rd * 8) * HW_;
#pragma unroll
    for (int kq = 0; kq < 2; ++kq)
#pragma unroll
      for (int ni = 0; ni < 2; ++ni)
        m0v[kq][ni] = mp[(size_t)(kq * 2) * HW_ + ni * 32];
  };

  auto COMP = [&](const short8 (&af)[2][2], const float (&m0v)[2][2]) {
#pragma unroll
    for (int kq = 0; kq < 2; ++kq) {
      short8 bv[2];
#pragma unroll
      for (int ni = 0; ni < 2; ++ni)
#pragma unroll
        for (int r = 0; r < 8; ++r)
          bv[ni][r] = f2bf(m0v[kq][ni] * mk[ni][r]);
#pragma unroll
      for (int mi = 0; mi < 2; ++mi)
#pragma unroll
        for (int ni = 0; ni < 2; ++ni)
          acc[mi][ni] = __builtin_amdgcn_mfma_f32_32x32x16_bf16(
              af[kq][mi], bv[ni], acc[mi][ni], 0, 0, 0);
    }
  };

  // 2-stage register pipeline, zero barriers in the main loop.
  LOAD(afA, m0A, 0);
#pragma unroll 1
  for (int rd = 0; rd < NRND; rd += 2) {
    LOAD(afB, m0B, rd + 1);
    COMP(afA, m0A);
    if (rd + 2 < NRND) LOAD(afA, m0A, rd + 2);
    COMP(afB, m0B);
  }

  // ---- K-split reduction + store ----
  // Pair (wk=0, wk=1) of same (wr,wc): each wave keeps mi==wk rows,
  // ships the other mi-half through LDS.
  int pairid = wr * 2 + wc;       // 0..3
  int other  = wk ^ 1;
  float* reg_w = &red[(pairid * 2 + other) * 2048];
#pragma unroll
  for (int ni = 0; ni < 2; ++ni)
#pragma unroll
    for (int q = 0; q < 4; ++q) {
      f32x4 v;
#pragma unroll
      for (int j = 0; j < 4; ++j) v[j] = acc[other][ni][q * 4 + j];
      *(f32x4*)&reg_w[(q * 128 + ni * 64 + lane) * 4] = v;
    }
  __syncthreads();

  const float* reg_r = &red[(pairid * 2 + wk) * 2048];
  size_t obase = (size_t)b * O_DIM * HW_ + p0;
#pragma unroll
  for (int ni = 0; ni < 2; ++ni) {
    f32x16 s = acc[wk][ni];
#pragma unroll
    for (int q = 0; q < 4; ++q) {
      f32x4 v = *(const f32x4*)&reg_r[(q * 128 + ni * 64 + lane) * 4];
#pragma unroll
      for (int j = 0; j < 4; ++j) s[q * 4 + j] += v[j];
    }
    int col = wc * 64 + ni * 32 + l31;
#pragma unroll
    for (int reg = 0; reg < 16; ++reg) {
      int row = o0 + wr * 64 + wk * 32 + (reg & 3) + 8 * (reg >> 2) + 4 * cr;
      out[obase + (size_t)row * HW_ + col] = s[reg];
    }
  }
}

extern "C" void kernel_launch(void* const* d_in, const int* in_sizes, int n_in,
                              void* d_out, int out_size, void* d_ws, size_t ws_size,
                              hipStream_t stream) {
  const float* mat0      = (const float*)d_in[0];   // [8,256,64,64]
  const float* mat1      = (const float*)d_in[1];   // [256,256,8]
  const float* mask      = (const float*)d_in[2];   // [8,64,64]
  const float* Alpha     = (const float*)d_in[3];   // [8]
  const int*   use_alpha = (const int*)d_in[4];     // [1]
  (void)in_sizes; (void)n_in; (void)out_size; (void)ws_size;

  short* Aprep = (short*)d_ws;                      // 1 MiB scratch
  float* outp  = (float*)d_out;

  prep_w_kernel<<<256, 256, 0, stream>>>(mat1, Alpha, use_alpha, Aprep);
  gemm_deform_kernel<<<512, 512, 0, stream>>>(mat0, Aprep, mask, outp);
}

// Round 5
// 88.434 us; speedup vs baseline: 1.0561x; 1.0561x over previous
//
#include <hip/hip_runtime.h>
#include <hip/hip_bf16.h>
#include <stdint.h>

// out[b,o,p] = sum_{r,c} mat0[b,c,p] * mat1[o,c,r]*Alpha[r] * mask[r,p]
// GEMM: M=256 (o), N=32768 (n=b*4096+p), K=2048 (k=c*8+r).
// A[o,k] = mat1[o,c,r]*Alpha[r]  (prepped bf16 in d_ws, layout [c][o][r])
// B[k,n] = mat0[b,c,p]*mask[r,p] synthesized IN REGISTERS per lane.
// Round 5: BM=64 x BN=128 tiles -> 1024 blocks (4 blocks/CU = 4 waves/SIMD),
// waves = wc2 x wk2 (in-block K-split), 32x32x16 MFMA, m0 ping-pong prefetch
// (2 rounds ahead), zero barriers in main loop, LDS K-reduction at epilogue.
// ALL register arrays statically indexed (R4's scratch bug was acc[runtime]).

typedef __attribute__((ext_vector_type(8)))  short short8;
typedef __attribute__((ext_vector_type(4)))  float f32x4;
typedef __attribute__((ext_vector_type(16))) float f32x16;

#define C_IN  256
#define HW_   4096
#define NRND  32    // K rounds; 8 c-planes per round, wk-wave handles 4

__device__ __forceinline__ short f2bf(float x) {
  union { __hip_bfloat16 h; short s; } u;
  u.h = __float2bfloat16(x);   // RNE; compiler pk-fuses into v_cvt_pk_bf16_f32
  return u.s;
}

__global__ __launch_bounds__(256) void prep_w_kernel(
    const float* __restrict__ mat1, const float* __restrict__ Alpha,
    const int* __restrict__ use_alpha, short* __restrict__ Aprep) {
  int t = blockIdx.x * 256 + threadIdx.x;   // o = t&255, c = t>>8
  int o = t & 255;
  int c = t >> 8;
  int ua = use_alpha[0];
  const float* src = mat1 + ((size_t)o * C_IN + c) * 8;
  short8 v;
#pragma unroll
  for (int r = 0; r < 8; ++r) {
    float s = ua ? Alpha[r] : 1.0f;
    v[r] = f2bf(src[r] * s);
  }
  // layout: slot (c*256 + o) holds 8 bf16 (r fastest)
  *(short8*)(Aprep + ((size_t)c * 256 + o) * 8) = v;
}

__global__ __launch_bounds__(256, 4) void gemm_deform_kernel(
    const float* __restrict__ mat0, const short* __restrict__ Aprep,
    const float* __restrict__ mask, float* __restrict__ out) {
  // epilogue K-reduction blob: [wc][lane][68] (stride 68 floats = 272B:
  // 16B-aligned for b128, 17-dword bank stride -> conflict-free)
  __shared__ float red[2][64][68];   // 34816 B

  int bid = blockIdx.x;
  int wg = (bid & 7) * 128 + (bid >> 3);   // XCD swizzle, 1024%8==0 bijective
  int tile_m = wg & 3;                     // M fastest: 4 M-tiles of one
  int tile_n = wg >> 2;                    //   tile_n share mat0 cols in L2
  int o0 = tile_m * 64;
  int n0 = tile_n * 128;
  int b  = n0 >> 12;
  int p0 = n0 & 4095;

  int t    = threadIdx.x;
  int lane = t & 63;
  int w    = t >> 6;        // 0..3
  int wk   = w & 1;         // K-half
  int wc   = w >> 1;        // N-half
  int l31  = lane & 31;
  int cr   = lane >> 5;     // c-plane parity within 16-k chunk

  int colb = p0 + wc * 64 + l31;
  float mk[2][8];
#pragma unroll
  for (int ni = 0; ni < 2; ++ni)
#pragma unroll
    for (int r = 0; r < 8; ++r)
      mk[ni][r] = mask[r * HW_ + colb + ni * 32];

  // A slot = c*256 + o; c = rd*8 + wk*4 + kq*2 + cr; o = o0 + mi*32 + l31
  const short8* __restrict__ Ap = (const short8*)Aprep;
  int aoff = (wk * 4 + cr) * 256 + o0 + l31;

  // mat0 source: plane c, column colb
  const float* __restrict__ m0b =
      mat0 + ((size_t)b * C_IN + wk * 4 + cr) * HW_ + colb;

  f32x16 acc[2][2];
#pragma unroll
  for (int mi = 0; mi < 2; ++mi)
#pragma unroll
    for (int ni = 0; ni < 2; ++ni)
#pragma unroll
      for (int j = 0; j < 16; ++j) acc[mi][ni][j] = 0.f;

  short8 afA[2][2], afB[2][2];     // [kq][mi]
  float  P0[2][2][2], P1[2][2][2]; // [round-in-pair][kq][ni]

  auto LOADA = [&](short8 (&af)[2][2], int rd) {
    int base = rd * 2048 + aoff;
#pragma unroll
    for (int kq = 0; kq < 2; ++kq)
#pragma unroll
      for (int mi = 0; mi < 2; ++mi)
        af[kq][mi] = Ap[base + kq * 512 + mi * 32];
  };

  auto LOADM = [&](float (&P)[2][2][2], int rd) {   // rounds rd, rd+1
#pragma unroll
    for (int rr = 0; rr < 2; ++rr) {
      const float* mp = m0b + (size_t)((rd + rr) * 8) * HW_;
#pragma unroll
      for (int kq = 0; kq < 2; ++kq)
#pragma unroll
        for (int ni = 0; ni < 2; ++ni)
          P[rr][kq][ni] = mp[(size_t)(kq * 2) * HW_ + ni * 32];
    }
  };

  auto COMP = [&](const short8 (&af)[2][2], const float (&m0v)[2][2]) {
#pragma unroll
    for (int kq = 0; kq < 2; ++kq) {
      short8 bv[2];
#pragma unroll
      for (int ni = 0; ni < 2; ++ni)
#pragma unroll
        for (int r = 0; r < 8; ++r)
          bv[ni][r] = f2bf(m0v[kq][ni] * mk[ni][r]);
#pragma unroll
      for (int mi = 0; mi < 2; ++mi)
#pragma unroll
        for (int ni = 0; ni < 2; ++ni)
          acc[mi][ni] = __builtin_amdgcn_mfma_f32_32x32x16_bf16(
              af[kq][mi], bv[ni], acc[mi][ni], 0, 0, 0);
    }
  };

  // ---- zero-barrier main loop; m0 2-rounds-ahead, A 1-round-ahead ----
  LOADM(P0, 0);
  LOADA(afA, 0);
#pragma unroll 1
  for (int rd = 0; rd < NRND; rd += 4) {
    // rounds rd, rd+1 from P0; prefetch P1 (rd+2, rd+3)
    LOADM(P1, rd + 2);
    LOADA(afB, rd + 1);
    COMP(afA, P0[0]);
    LOADA(afA, rd + 2);
    COMP(afB, P0[1]);
    // rounds rd+2, rd+3 from P1; prefetch P0 (rd+4, rd+5)
    if (rd + 4 < NRND) LOADM(P0, rd + 4);
    LOADA(afB, rd + 3);
    COMP(afA, P1[0]);
    if (rd + 4 < NRND) LOADA(afA, rd + 4);
    COMP(afB, P1[1]);
  }

  // ---- K-split reduction (static indices only) ----
  if (wk == 1) {
    float* dst = &red[wc][lane][0];
#pragma unroll
    for (int mi = 0; mi < 2; ++mi)
#pragma unroll
      for (int ni = 0; ni < 2; ++ni)
#pragma unroll
        for (int q = 0; q < 4; ++q) {
          f32x4 v;
#pragma unroll
          for (int j = 0; j < 4; ++j) v[j] = acc[mi][ni][q * 4 + j];
          *(f32x4*)&dst[(mi * 2 + ni) * 16 + q * 4] = v;
        }
  }
  __syncthreads();
  if (wk == 0) {
    const float* src = &red[wc][lane][0];
#pragma unroll
    for (int mi = 0; mi < 2; ++mi)
#pragma unroll
      for (int ni = 0; ni < 2; ++ni)
#pragma unroll
        for (int q = 0; q < 4; ++q) {
          f32x4 v = *(const f32x4*)&src[(mi * 2 + ni) * 16 + q * 4];
#pragma unroll
          for (int j = 0; j < 4; ++j) acc[mi][ni][q * 4 + j] += v[j];
        }
    size_t obase = (size_t)b * 256 * HW_;
#pragma unroll
    for (int mi = 0; mi < 2; ++mi) {
#pragma unroll
      for (int ni = 0; ni < 2; ++ni) {
        int col = colb + ni * 32;
#pragma unroll
        for (int reg = 0; reg < 16; ++reg) {
          int row = o0 + mi * 32 + (reg & 3) + 8 * (reg >> 2) + 4 * cr;
          out[obase + (size_t)row * HW_ + col] = acc[mi][ni][reg];
        }
      }
    }
  }
}

extern "C" void kernel_launch(void* const* d_in, const int* in_sizes, int n_in,
                              void* d_out, int out_size, void* d_ws, size_t ws_size,
                              hipStream_t stream) {
  const float* mat0      = (const float*)d_in[0];   // [8,256,64,64]
  const float* mat1      = (const float*)d_in[1];   // [256,256,8]
  const float* mask      = (const float*)d_in[2];   // [8,64,64]
  const float* Alpha     = (const float*)d_in[3];   // [8]
  const int*   use_alpha = (const int*)d_in[4];     // [1]
  (void)in_sizes; (void)n_in; (void)out_size; (void)ws_size;

  short* Aprep = (short*)d_ws;                      // 1 MiB scratch
  float* outp  = (float*)d_out;

  prep_w_kernel<<<256, 256, 0, stream>>>(mat1, Alpha, use_alpha, Aprep);
  gemm_deform_kernel<<<1024, 256, 0, stream>>>(mat0, Aprep, mask, outp);
}

// Round 6
// 57.410 us; speedup vs baseline: 1.6268x; 1.5404x over previous
//
#include <hip/hip_runtime.h>
#include <hip/hip_bf16.h>
#include <stdint.h>

// out[b,o,p] = sum_{r,c} mat0[b,c,p] * mat1[o,c,r]*Alpha[r] * mask[r,p]
// GEMM: M=256 (o), N=32768 (n=b*4096+p), K=2048 (k=c*8+r).
// A[o,k] = mat1[o,c,r]*Alpha[r]  (prepped bf16 in d_ws, layout [c][o][r])
// B[k,n] = mat0[b,c,p]*mask[r,p] synthesized IN REGISTERS per lane.
// Round 6: fit 128-VGPR cap honestly. 512-thread blocks (8 waves = wr2 x wc4),
// BM=BN=128 -> per-wave 64x32 out (acc=32 VGPRs, mk=8). Zero LDS, zero
// barriers, in-place per-kq operand reload (no ping-pong doubling). Grid =
// 512 tiles exactly = 2 blocks/CU = 4 waves/SIMD, single generation, no tail.

typedef __attribute__((ext_vector_type(8)))  short short8;
typedef __attribute__((ext_vector_type(16))) float f32x16;

#define C_IN  256
#define HW_   4096
#define NRND  32    // K rounds of 64 (8 c-planes per round)

__device__ __forceinline__ short f2bf(float x) {
  union { __hip_bfloat16 h; short s; } u;
  u.h = __float2bfloat16(x);   // RNE; compiler pk-fuses into v_cvt_pk_bf16_f32
  return u.s;
}

__global__ __launch_bounds__(256) void prep_w_kernel(
    const float* __restrict__ mat1, const float* __restrict__ Alpha,
    const int* __restrict__ use_alpha, short* __restrict__ Aprep) {
  int t = blockIdx.x * 256 + threadIdx.x;   // o = t&255, c = t>>8
  int o = t & 255;
  int c = t >> 8;
  int ua = use_alpha[0];
  const float* src = mat1 + ((size_t)o * C_IN + c) * 8;
  short8 v;
#pragma unroll
  for (int r = 0; r < 8; ++r) {
    float s = ua ? Alpha[r] : 1.0f;
    v[r] = f2bf(src[r] * s);
  }
  // layout: slot (c*256 + o) holds 8 bf16 (r fastest)
  *(short8*)(Aprep + ((size_t)c * 256 + o) * 8) = v;
}

__global__ __launch_bounds__(512, 4) void gemm_deform_kernel(
    const float* __restrict__ mat0, const short* __restrict__ Aprep,
    const float* __restrict__ mask, float* __restrict__ out) {
  int bid = blockIdx.x;
  int wg = (bid & 7) * 64 + (bid >> 3);   // XCD swizzle (512%8==0, bijective)
  int tile_m = wg & 1;                    // M fastest: pair shares mat0 cols
  int tile_n = wg >> 1;                   // 0..255; XCD mat0 slice ~4MB -> its L2
  int o0 = tile_m * 128;
  int n0 = tile_n * 128;
  int b  = n0 >> 12;
  int p0 = n0 & 4095;

  int t    = threadIdx.x;
  int lane = t & 63;
  int w    = t >> 6;        // 0..7
  int wc   = w & 3;         // 4 column groups of 32
  int wr   = w >> 2;        // 2 row groups of 64
  int l31  = lane & 31;
  int cr   = lane >> 5;     // k-half within MFMA K=16 (c-plane parity)

  // this wave's single 32-column group; lane-resident mask values
  int col = p0 + wc * 32 + l31;
  float mk[8];
#pragma unroll
  for (int r = 0; r < 8; ++r) mk[r] = mask[r * HW_ + col];

  // A slot = c*256 + o; c = rd*8 + kq*2 + cr; o = o0 + wr*64 + mi*32 + l31
  const short8* __restrict__ Ap = (const short8*)Aprep;
  int aoff = cr * 256 + o0 + wr * 64 + l31;

  // mat0 scalar source: plane c = rd*8 + kq*2 + cr, column col
  const float* __restrict__ m0b =
      mat0 + ((size_t)b * C_IN + cr) * HW_ + col;

  f32x16 acc[2];   // [mi] -> rows o0+wr*64+mi*32+..., cols col (32-group)
#pragma unroll
  for (int mi = 0; mi < 2; ++mi)
#pragma unroll
    for (int j = 0; j < 16; ++j) acc[mi][j] = 0.f;

  short8 af[4][2];   // [kq][mi], reloaded in place each kq-phase
  float  P[4];       // [kq] mat0 scalars, reloaded in place

  // ---- prologue: round 0 operands ----
#pragma unroll
  for (int kq = 0; kq < 4; ++kq) {
#pragma unroll
    for (int mi = 0; mi < 2; ++mi)
      af[kq][mi] = Ap[aoff + kq * 512 + mi * 32];
    P[kq] = m0b[(size_t)(kq * 2) * HW_];
  }

  // ---- main loop: zero barriers; per-kq compute then in-place prefetch ----
#pragma unroll 1
  for (int rd = 0; rd < NRND - 1; ++rd) {
    int abase = (rd + 1) * 2048 + aoff;
    const float* mnext = m0b + (size_t)((rd + 1) * 8) * HW_;
#pragma unroll
    for (int kq = 0; kq < 4; ++kq) {
      short8 bv;
#pragma unroll
      for (int r = 0; r < 8; ++r) bv[r] = f2bf(P[kq] * mk[r]);
      acc[0] = __builtin_amdgcn_mfma_f32_32x32x16_bf16(af[kq][0], bv, acc[0], 0, 0, 0);
      acc[1] = __builtin_amdgcn_mfma_f32_32x32x16_bf16(af[kq][1], bv, acc[1], 0, 0, 0);
      // in-place reload for round rd+1 (3 kq-phases of latency cover)
      af[kq][0] = Ap[abase + kq * 512];
      af[kq][1] = Ap[abase + kq * 512 + 32];
      P[kq] = mnext[(size_t)(kq * 2) * HW_];
    }
  }
  // ---- final round (no prefetch) ----
#pragma unroll
  for (int kq = 0; kq < 4; ++kq) {
    short8 bv;
#pragma unroll
    for (int r = 0; r < 8; ++r) bv[r] = f2bf(P[kq] * mk[r]);
    acc[0] = __builtin_amdgcn_mfma_f32_32x32x16_bf16(af[kq][0], bv, acc[0], 0, 0, 0);
    acc[1] = __builtin_amdgcn_mfma_f32_32x32x16_bf16(af[kq][1], bv, acc[1], 0, 0, 0);
  }

  // ---- epilogue: 32x32 C/D layout col=lane&31, row=(reg&3)+8*(reg>>2)+4*cr ----
  size_t obase = (size_t)b * 256 * HW_ + col;
#pragma unroll
  for (int mi = 0; mi < 2; ++mi) {
#pragma unroll
    for (int reg = 0; reg < 16; ++reg) {
      int row = o0 + wr * 64 + mi * 32 + (reg & 3) + 8 * (reg >> 2) + 4 * cr;
      out[obase + (size_t)row * HW_] = acc[mi][reg];
    }
  }
}

extern "C" void kernel_launch(void* const* d_in, const int* in_sizes, int n_in,
                              void* d_out, int out_size, void* d_ws, size_t ws_size,
                              hipStream_t stream) {
  const float* mat0      = (const float*)d_in[0];   // [8,256,64,64]
  const float* mat1      = (const float*)d_in[1];   // [256,256,8]
  const float* mask      = (const float*)d_in[2];   // [8,64,64]
  const float* Alpha     = (const float*)d_in[3];   // [8]
  const int*   use_alpha = (const int*)d_in[4];     // [1]
  (void)in_sizes; (void)n_in; (void)out_size; (void)ws_size;

  short* Aprep = (short*)d_ws;                      // 1 MiB scratch
  float* outp  = (float*)d_out;

  prep_w_kernel<<<256, 256, 0, stream>>>(mat1, Alpha, use_alpha, Aprep);
  gemm_deform_kernel<<<512, 512, 0, stream>>>(mat0, Aprep, mask, outp);
}